// Round 5
// baseline (8036.700 us; speedup 1.0000x reference)
//
#include <hip/hip_runtime.h>
#include <stdint.h>
#include <math.h>

// ---------------- constants ----------------
#define SCALE  0.125f

typedef __bf16 bf16;
typedef __bf16 bf16x8 __attribute__((ext_vector_type(8)));
typedef float  f32x4  __attribute__((ext_vector_type(4)));

__device__ __forceinline__ ushort f2b(float f) {
  union { float f; uint32_t u; } v; v.f = f;
  uint32_t u = v.u;
  return (ushort)((u + 0x7fffu + ((u >> 16) & 1u)) >> 16);
}
__device__ __forceinline__ float b2f(ushort s) {
  union { uint32_t u; float f; } v; v.u = ((uint32_t)s) << 16;
  return v.f;
}
__device__ __forceinline__ void g2l16(const ushort* g, ushort* l) {
  __builtin_amdgcn_global_load_lds(
      (const __attribute__((address_space(1))) void*)g,
      (__attribute__((address_space(3))) void*)l, 16, 0, 0);
}
// A&S 7.1.26 erf, |eps| <= 1.5e-7 (far below bf16 rounding). v_rcp + v_exp.
__device__ __forceinline__ float erf_fast(float x) {
  float ax = fabsf(x);
  float t  = __builtin_amdgcn_rcpf(1.0f + 0.3275911f * ax);
  float p  = t * (0.254829592f + t * (-0.284496736f + t * (1.421413741f +
             t * (-1.453152027f + t * 1.061405429f))));
  float e  = __expf(-ax * ax);
  float r  = 1.0f - p * e;
  return copysignf(r, x);
}

// ---------------- conversion kernels ----------------
// x: (S,B,N,D) f32 -> xb: (S,N,B,D) bf16
__global__ __launch_bounds__(256) void conv_x_kernel(const float* __restrict__ x,
                                                     ushort* __restrict__ xb) {
  int idx = blockIdx.x * 256 + threadIdx.x;
  int d4 = idx & 255;
  int n  = (idx >> 8) & 31;
  int b  = (idx >> 13) & 127;
  int s  = idx >> 20;
  float4 v = *(const float4*)(x + (size_t)(((s*128 + b)*32 + n) << 10) + (d4 << 2));
  ushort4 o;
  o.x = f2b(v.x); o.y = f2b(v.y); o.z = f2b(v.z); o.w = f2b(v.w);
  *(ushort4*)(xb + (size_t)(((s*32 + n)*128 + b) << 10) + (d4 << 2)) = o;
}

__global__ __launch_bounds__(256) void conv_q_kernel(const float* __restrict__ q,
                                                     ushort* __restrict__ qb) {
  int idx = blockIdx.x * 256 + threadIdx.x;
  float4 v = *(const float4*)(q + (size_t)idx * 4);
  ushort4 o;
  o.x = f2b(v.x); o.y = f2b(v.y); o.z = f2b(v.z); o.w = f2b(v.w);
  *(ushort4*)(qb + (size_t)idx * 4) = o;
}

// Wt[r][k] = W[k][srccol(r)] (bf16).
// mode 1 = W1 GLU interleave on 64-row groups: group g6 = r>>6, w = r&63:
//   w<32 -> a col g6*32+w ; w>=32 -> gate col 4096 + g6*32 + (w-32).
__global__ __launch_bounds__(256) void transpose_w_kernel(const float* __restrict__ W,
                                                          ushort* __restrict__ Wt,
                                                          int K, int N, int mode) {
  __shared__ float tile[32][33];
  int rt = blockIdx.x, kt = blockIdx.y;
  int r0 = rt * 32;
  int tx = threadIdx.x & 31, ty = threadIdx.x >> 5;
  int src;
  if (mode == 1) {
    int rp = r0 + tx;
    int g6 = rp >> 6, w = rp & 63;
    src = (w < 32) ? (g6*32 + w) : (4096 + g6*32 + (w - 32));
  } else {
    src = r0 + tx;
  }
  for (int i = ty; i < 32; i += 8)
    tile[i][tx] = W[(size_t)(kt*32 + i) * N + src];
  __syncthreads();
  for (int i = ty; i < 32; i += 8)
    Wt[(size_t)(r0 + i) * K + kt*32 + tx] = f2b(tile[tx][i]);
}

// ---------------- main GEMM: 256x256 tile, A-in-LDS + B-direct-to-regs ------
// bf16 A [MxK] x bf16 Bt [NxK]. 512 threads = 8 waves (2M x 4N); per-wave C =
// 128x64 = 8x4 fragments of 16x16 (mfma_f32_16x16x32_bf16). BK=64.
//
// ROUND-4 LESSON (LDS-BW-bound): with A+B both LDS-staged, per-tile ds_read
// demand (192 KB ~ 2300 cyc @85 B/cyc) >= MFMA work (~2100 cyc); every barrier
// schedule variant (r2/r3/r4) pinned at MfmaUtil 37-41%. Fix is structural:
//  - B goes global->VGPR directly (per-lane 16B fragment gather; layout needs
//    no swizzle). LDS read drops to 128 KB/tile, DMA writes halve. B rows are
//    re-read 2x per block (wm pair) but are L1/L2-resident.
//  - LDS halves to 64 KiB (A only, double-buffered) -> 2 blocks/CU for G1/G2,
//    4 waves/SIMD: cross-block TLP hides both LDS and MFMA bursts.
//  - All staging for tile t+1 (4 A-DMA + 8 B-reg loads) is issued inside tile
//    t and drained by ONE vmcnt(0) at the boundary (everything outstanding is
//    needed at t+1 P0, so the drain is cheap and the counted-vmcnt ordering
//    fragility disappears).
// LDS layout per tile: row r = 128B = 8 granules of 16B; granule g of row r at
// slot g^(r&7) (bank-conflict-free ds_read_b128; counter-verified 0 conflicts).
// 16x16x32 fragment: lane (qq=lane>>4, c15=lane&15) reads row c15, k-chunk
// kh*32 + qq*8 -> granule kh*4 + qq.
// Hazards: (pub) own vmcnt(0) retires own A-DMA LDS writes, barrier publishes
// to other waves; (WAR) lgkmcnt(0) before boundary barrier = own reads of cur
// done, and t+1 stages into cur only after its P1 (two barriers later).
// Keep r3's 4-barrier pacing (empirically best) + setprio around MFMA.
// EPI 0: store bf16 -> outb (stride NCOLS)
// EPI 1: in-register GLU (64-group-interleaved W1t) -> hidden bf16 (stride 4096)
// EPI 2: float out = acc + bias[col] + resid (stride NCOLS)
template <int EPI, int K, int NCOLS>
__global__ __launch_bounds__(512, 4) void gemm256(const ushort* __restrict__ A,
                                                  const ushort* __restrict__ Bt,
                                                  float* __restrict__ outf,
                                                  ushort* __restrict__ outb,
                                                  const float* __restrict__ bias,
                                                  const float* __restrict__ resid) {
  __shared__ ushort As[2][16384];
  constexpr int NT  = K / 64;
  constexpr int nBn = NCOLS / 256;

  // XCD-aware swizzle (all grids are multiples of 8)
  const int nwg = (int)gridDim.x;
  const int bid = (int)blockIdx.x;
  const int wg  = (bid & 7) * (nwg >> 3) + (bid >> 3);
  const int bm = wg / nBn, bn = wg % nBn;

  const int t = threadIdx.x;
  const int wave = t >> 6, lane = t & 63;
  const int wm = wave >> 2, wn = wave & 3;
  const int c15 = lane & 15, qq = lane >> 4;
  const int swz = c15 & 7;

  // A staging: thread t -> row (t>>3) within 64-row call block, slot t&7,
  // source granule (t&7)^(row&7)
  const int rowc = t >> 3;
  const int kg = (t & 7) ^ (rowc & 7);
  const ushort* ag = A + (size_t)(bm*256 + rowc) * K + kg*8;
  // B direct fragment base: row (bn*256 + wn*64 + ni*16 + c15), k-off qq*8
  const ushort* bgf = Bt + (size_t)(bn*256 + wn*64 + c15) * K + qq*8;

  f32x4 acc[8][4] = {};
  bf16x8 bA[4][2], bB[4][2];   // current / next B fragments (static idx only)

#define LDA_F(buf, mi, kh) \
  (*(const bf16x8*)(&As[buf][(wm*128 + (mi)*16 + c15)*64 + ((((kh)*4 + qq) ^ swz)*8)]))
#define LDBG(ni, kh, kt) \
  (*(const bf16x8*)(bgf + (size_t)(ni)*16*K + (size_t)(kt)*64 + (kh)*32))
#define STG_A(c, buf, kt) \
  g2l16(ag + (size_t)(c)*64*K + (size_t)(kt)*64, &As[buf][(c)*4096 + wave*512])

#define CFENCE asm volatile("" ::: "memory")

#define MFMA8(p, aa, ab, kh, BC) \
  _Pragma("unroll") \
  for (int ni = 0; ni < 4; ++ni) { \
    acc[2*(p)][ni]   = __builtin_amdgcn_mfma_f32_16x16x32_bf16((aa), BC[ni][(kh)], acc[2*(p)][ni],   0, 0, 0); \
    acc[2*(p)+1][ni] = __builtin_amdgcn_mfma_f32_16x16x32_bf16((ab), BC[ni][(kh)], acc[2*(p)+1][ni], 0, 0, 0); \
  }

  // prologue: stage A(tile0) + load B(tile0); drain; publish
  STG_A(0, 0, 0); STG_A(1, 0, 0); STG_A(2, 0, 0); STG_A(3, 0, 0);
  bA[0][0] = LDBG(0,0,0); bA[1][0] = LDBG(1,0,0);
  bA[2][0] = LDBG(2,0,0); bA[3][0] = LDBG(3,0,0);
  bA[0][1] = LDBG(0,1,0); bA[1][1] = LDBG(1,1,0);
  bA[2][1] = LDBG(2,1,0); bA[3][1] = LDBG(3,1,0);
  asm volatile("s_waitcnt vmcnt(0)" ::: "memory");
  __builtin_amdgcn_s_barrier();
  CFENCE;

#define TILE(kt, cur, BC, BN) { \
    const int nx_ = (cur) ^ 1; \
    const int tn_ = ((kt) + 1 == NT) ? 0 : ((kt) + 1); \
    /* ---- P0: B(next) -> regs; A mi0-3 kh0; MFMA quads 0,1 kh0 ---- */ { \
      BN[0][0] = LDBG(0,0,tn_); BN[1][0] = LDBG(1,0,tn_); \
      BN[2][0] = LDBG(2,0,tn_); BN[3][0] = LDBG(3,0,tn_); \
      BN[0][1] = LDBG(0,1,tn_); BN[1][1] = LDBG(1,1,tn_); \
      BN[2][1] = LDBG(2,1,tn_); BN[3][1] = LDBG(3,1,tn_); \
      bf16x8 a0 = LDA_F(cur, 0, 0), a1 = LDA_F(cur, 1, 0); \
      bf16x8 a2 = LDA_F(cur, 2, 0), a3 = LDA_F(cur, 3, 0); \
      __builtin_amdgcn_s_setprio(1); \
      MFMA8(0, a0, a1, 0, BC); MFMA8(1, a2, a3, 0, BC); \
      __builtin_amdgcn_s_setprio(0); \
      __builtin_amdgcn_s_barrier(); \
    } \
    /* ---- P1: A mi0-3 kh1; stage A0,A1(next); MFMA kh1 ---- */ { \
      bf16x8 a0 = LDA_F(cur, 0, 1), a1 = LDA_F(cur, 1, 1); \
      bf16x8 a2 = LDA_F(cur, 2, 1), a3 = LDA_F(cur, 3, 1); \
      STG_A(0, nx_, tn_); STG_A(1, nx_, tn_); \
      __builtin_amdgcn_s_setprio(1); \
      MFMA8(0, a0, a1, 1, BC); MFMA8(1, a2, a3, 1, BC); \
      __builtin_amdgcn_s_setprio(0); \
      __builtin_amdgcn_s_barrier(); \
    } \
    /* ---- P2: A mi4-7 kh0; stage A2,A3(next); MFMA ---- */ { \
      bf16x8 a0 = LDA_F(cur, 4, 0), a1 = LDA_F(cur, 5, 0); \
      bf16x8 a2 = LDA_F(cur, 6, 0), a3 = LDA_F(cur, 7, 0); \
      STG_A(2, nx_, tn_); STG_A(3, nx_, tn_); \
      __builtin_amdgcn_s_setprio(1); \
      MFMA8(2, a0, a1, 0, BC); MFMA8(3, a2, a3, 0, BC); \
      __builtin_amdgcn_s_setprio(0); \
      __builtin_amdgcn_s_barrier(); \
    } \
    /* ---- P3: A mi4-7 kh1; MFMA; lgkm0 + vmcnt(0) + BARRIER ---- */ { \
      bf16x8 a0 = LDA_F(cur, 4, 1), a1 = LDA_F(cur, 5, 1); \
      bf16x8 a2 = LDA_F(cur, 6, 1), a3 = LDA_F(cur, 7, 1); \
      __builtin_amdgcn_s_setprio(1); \
      MFMA8(2, a0, a1, 1, BC); MFMA8(3, a2, a3, 1, BC); \
      __builtin_amdgcn_s_setprio(0); \
      asm volatile("s_waitcnt lgkmcnt(0)" ::: "memory"); \
      asm volatile("s_waitcnt vmcnt(0)" ::: "memory"); \
      __builtin_amdgcn_s_barrier(); \
      CFENCE; \
    } \
  }

#pragma unroll 1
  for (int kt = 0; kt < NT; kt += 2) {
    TILE(kt, 0, bA, bB);
    TILE(kt + 1, 1, bB, bA);
  }
  // wrap-stage DMAs already drained by the last boundary vmcnt(0)
  asm volatile("s_waitcnt vmcnt(0)" ::: "memory");

#undef TILE
#undef MFMA8
#undef CFENCE
#undef STG_A
#undef LDBG
#undef LDA_F

  // C/D layout (m89/m91): col = lane&15, row = (lane>>4)*4 + reg
  if (EPI == 0) {
#pragma unroll
    for (int mi = 0; mi < 8; ++mi) {
      int row0 = bm*256 + wm*128 + mi*16 + qq*4;
#pragma unroll
      for (int j = 0; j < 4; ++j) {
#pragma unroll
        for (int ni = 0; ni < 4; ++ni) {
          int col = bn*256 + wn*64 + ni*16 + c15;
          outb[(size_t)(row0 + j) * NCOLS + col] = f2b(acc[mi][ni][j]);
        }
      }
    }
  } else if (EPI == 1) {
    // wave's 64-col slice == one GLU 64-group: g6 = bn*4 + wn.
    // ni 0,1 = 'a' (cols g6*32 + ni*16 + c15); ni 2,3 = gate (same hidden col).
    const int g6 = bn*4 + wn;
    const int hcol0 = g6*32 + c15;
    float ba0 = bias[hcol0],        ba1 = bias[hcol0 + 16];
    float bg0 = bias[4096 + hcol0], bg1 = bias[4096 + hcol0 + 16];
#pragma unroll
    for (int mi = 0; mi < 8; ++mi) {
      int row0 = bm*256 + wm*128 + mi*16 + qq*4;
#pragma unroll
      for (int j = 0; j < 4; ++j) {
        float a0 = acc[mi][0][j] + ba0, g0 = acc[mi][2][j] + bg0;
        float a1 = acc[mi][1][j] + ba1, g1 = acc[mi][3][j] + bg1;
        float ge0 = 0.5f * g0 * (1.0f + erf_fast(g0 * 0.70710678118654752f));
        float ge1 = 0.5f * g1 * (1.0f + erf_fast(g1 * 0.70710678118654752f));
        size_t rb = (size_t)(row0 + j) * 4096;
        outb[rb + hcol0]      = f2b(a0 * ge0);
        outb[rb + hcol0 + 16] = f2b(a1 * ge1);
      }
    }
  } else {
    float bc[4];
#pragma unroll
    for (int ni = 0; ni < 4; ++ni) bc[ni] = bias[bn*256 + wn*64 + ni*16 + c15];
#pragma unroll
    for (int mi = 0; mi < 8; ++mi) {
      int row0 = bm*256 + wm*128 + mi*16 + qq*4;
#pragma unroll
      for (int j = 0; j < 4; ++j) {
#pragma unroll
        for (int ni = 0; ni < 4; ++ni) {
          int col = bn*256 + wn*64 + ni*16 + c15;
          size_t o = (size_t)(row0 + j) * NCOLS + col;
          outf[o] = acc[mi][ni][j] + bc[ni] + resid[o];
        }
      }
    }
  }
}

// ---------------- attention ----------------
__global__ __launch_bounds__(256) void attn_kernel(const ushort* __restrict__ kv,
                                                   const ushort* __restrict__ qb,
                                                   const int* __restrict__ mask,
                                                   float* __restrict__ out) {
  __shared__ ushort Ks[128 * 72];
  __shared__ ushort Vt[64 * 136];
  __shared__ ushort Ps[64 * 136];
  __shared__ float  Mrow[128];

  const int bid = blockIdx.x;
  const int h = bid & 15, n = (bid >> 4) & 31, s = bid >> 9;
  const size_t kvbase = (size_t)((s*32 + n) * 128) * 2048;
  const int t = threadIdx.x, wave = t >> 6, lane = t & 63;
  const int qq = lane >> 4, r = lane & 15;

  if (t < 128) Mrow[t] = (mask[s*128 + t] == 0) ? 1.0f : 0.0f;

  for (int c = t; c < 1024; c += 256) {
    int b = c >> 3, d0 = (c & 7) * 8;
    uint4 v = *(const uint4*)(kv + kvbase + (size_t)b * 2048 + h*64 + d0);
    *(uint4*)(Ks + b*72 + d0) = v;
  }
  {
    int b = t & 127, dh = t >> 7;
    for (int jj = 0; jj < 32; jj += 8) {
      uint4 v = *(const uint4*)(kv + kvbase + (size_t)b * 2048 + 1024 + h*64 + dh*32 + jj);
      const ushort* pv = (const ushort*)&v;
#pragma unroll
      for (int u8 = 0; u8 < 8; u8++)
        Vt[(dh*32 + jj + u8)*136 + b] = pv[u8];
    }
  }
  __syncthreads();

  bf16x8 aq[2];
#pragma unroll
  for (int st = 0; st < 2; st++)
    aq[st] = *(const bf16x8*)(qb + (size_t)(wave*16 + r) * 1024 + h*64 + st*32 + qq*8);
  f32x4 sim[8];
#pragma unroll
  for (int jt = 0; jt < 8; jt++) {
    f32x4 c = {};
#pragma unroll
    for (int st = 0; st < 2; st++) {
      bf16x8 bk = *(const bf16x8*)(Ks + (jt*16 + r)*72 + st*32 + qq*8);
      c = __builtin_amdgcn_mfma_f32_16x16x32_bf16(aq[st], bk, c, 0, 0, 0);
    }
    sim[jt] = c;
  }

#pragma unroll
  for (int jt = 0; jt < 8; jt++) {
    float mflag = Mrow[jt*16 + r];
#pragma unroll
    for (int ii = 0; ii < 4; ii++) {
      float v = sim[jt][ii] * SCALE;
      sim[jt][ii] = (mflag > 0.5f) ? -1e10f : v;
    }
  }
  float mx[4] = {-3.0e38f, -3.0e38f, -3.0e38f, -3.0e38f};
#pragma unroll
  for (int jt = 0; jt < 8; jt++)
#pragma unroll
    for (int ii = 0; ii < 4; ii++) mx[ii] = fmaxf(mx[ii], sim[jt][ii]);
#pragma unroll
  for (int m = 1; m < 16; m <<= 1)
#pragma unroll
    for (int ii = 0; ii < 4; ii++) mx[ii] = fmaxf(mx[ii], __shfl_xor(mx[ii], m));
  float sm[4] = {0.f, 0.f, 0.f, 0.f};
#pragma unroll
  for (int jt = 0; jt < 8; jt++)
#pragma unroll
    for (int ii = 0; ii < 4; ii++) {
      float e = expf(sim[jt][ii] - mx[ii]);
      sim[jt][ii] = e;
      sm[ii] += e;
    }
#pragma unroll
  for (int m = 1; m < 16; m <<= 1)
#pragma unroll
    for (int ii = 0; ii < 4; ii++) sm[ii] += __shfl_xor(sm[ii], m);
#pragma unroll
  for (int ii = 0; ii < 4; ii++) sm[ii] = 1.0f / sm[ii];
#pragma unroll
  for (int jt = 0; jt < 8; jt++)
#pragma unroll
    for (int ii = 0; ii < 4; ii++)
      Ps[(wave*16 + qq*4 + ii)*136 + jt*16 + r] = f2b(sim[jt][ii] * sm[ii]);
  __syncthreads();

  f32x4 o[4] = {};
#pragma unroll
  for (int kst = 0; kst < 4; kst++) {
    bf16x8 ap = *(const bf16x8*)(Ps + (wave*16 + r)*136 + kst*32 + qq*8);
#pragma unroll
    for (int jt2 = 0; jt2 < 4; jt2++) {
      bf16x8 bv = *(const bf16x8*)(Vt + (jt2*16 + r)*136 + kst*32 + qq*8);
      o[jt2] = __builtin_amdgcn_mfma_f32_16x16x32_bf16(ap, bv, o[jt2], 0, 0, 0);
    }
  }
  const size_t orow0 = (size_t)((s*32 + n) * 64);
#pragma unroll
  for (int jt2 = 0; jt2 < 4; jt2++)
#pragma unroll
    for (int ii = 0; ii < 4; ii++) {
      int qr = wave*16 + qq*4 + ii;
      int d  = jt2*16 + r;
      out[(orow0 + qr) * 1024 + h*64 + d] = o[jt2][ii];
    }
}

// ---------------- LayerNorm (in-place) + bf16 copy ----------------
__global__ __launch_bounds__(256) void ln_kernel(float* __restrict__ y,
                                                 ushort* __restrict__ yb,
                                                 const float* __restrict__ g,
                                                 const float* __restrict__ b) {
  __shared__ float r1[4], r2[4];
  const int row = blockIdx.x, t = threadIdx.x;
  const int wave = t >> 6, lane = t & 63;
  float* p = y + (size_t)row * 1024;
  float4 v = *(const float4*)(p + t*4);
  float s1 = v.x + v.y + v.z + v.w;
  float s2 = v.x*v.x + v.y*v.y + v.z*v.z + v.w*v.w;
#pragma unroll
  for (int m = 1; m < 64; m <<= 1) { s1 += __shfl_xor(s1, m); s2 += __shfl_xor(s2, m); }
  if (lane == 0) { r1[wave] = s1; r2[wave] = s2; }
  __syncthreads();
  s1 = r1[0] + r1[1] + r1[2] + r1[3];
  s2 = r2[0] + r2[1] + r2[2] + r2[3];
  float mu  = s1 * (1.0f/1024.0f);
  float var = s2 * (1.0f/1024.0f) - mu*mu;
  float inv = rsqrtf(var + 1e-5f);
  float4 gg = *(const float4*)(g + t*4);
  float4 bb = *(const float4*)(b + t*4);
  float4 o;
  o.x = (v.x - mu)*inv*gg.x + bb.x;
  o.y = (v.y - mu)*inv*gg.y + bb.y;
  o.z = (v.z - mu)*inv*gg.z + bb.z;
  o.w = (v.w - mu)*inv*gg.w + bb.w;
  *(float4*)(p + t*4) = o;
  ushort4 ob; ob.x = f2b(o.x); ob.y = f2b(o.y); ob.z = f2b(o.z); ob.w = f2b(o.w);
  *(ushort4*)(yb + (size_t)row * 1024 + t*4) = ob;
}

// ---------------- launcher ----------------
extern "C" void kernel_launch(void* const* d_in, const int* in_sizes, int n_in,
                              void* d_out, int out_size, void* d_ws, size_t ws_size,
                              hipStream_t stream) {
  const float* x    = (const float*)d_in[0];
  const int*   mask = (const int*)  d_in[1];
  const float* q    = (const float*)d_in[2];
  const float* Wkv  = (const float*)d_in[3];
  const float* lng  = (const float*)d_in[4];
  const float* lnb  = (const float*)d_in[5];
  const float* W1   = (const float*)d_in[6];
  const float* b1   = (const float*)d_in[7];
  const float* W2   = (const float*)d_in[8];
  const float* b2   = (const float*)d_in[9];
  float* out = (float*)d_out;
  char* ws = (char*)d_ws;

  ushort* xb   = (ushort*)(ws);               // 64 MiB; dead after G1
  float*  yf   = (float*) (ws);               // alias: attn out / y
  ushort* kvb  = (ushort*)(ws + 67108864);    // 128 MiB; dead after attn
  ushort* hid  = (ushort*)(ws + 67108864);    // alias: hidden bf16
  ushort* yb   = (ushort*)(ws + 201326592);   // 32 MiB
  ushort* wkvt = (ushort*)(ws + 234881024);   // 4 MiB
  ushort* w1t  = (ushort*)(ws + 239075328);   // 16 MiB (GLU 64-group interleave)
  ushort* w2t  = (ushort*)(ws + 255852544);   // 8 MiB
  ushort* qb   = (ushort*)(ws + 264241152);   // 128 KiB

  conv_x_kernel<<<32768, 256, 0, stream>>>(x, xb);
  conv_q_kernel<<<64, 256, 0, stream>>>(q, qb);
  transpose_w_kernel<<<dim3(64, 32),  256, 0, stream>>>(Wkv, wkvt, 1024, 2048, 0);
  transpose_w_kernel<<<dim3(256, 32), 256, 0, stream>>>(W1,  w1t,  1024, 8192, 1);
  transpose_w_kernel<<<dim3(32, 128), 256, 0, stream>>>(W2,  w2t,  4096, 1024, 0);

  // G1: (32768x1024) @ (1024x2048) -> kv bf16.  grid 128*8 = 1024
  gemm256<0, 1024, 2048><<<1024, 512, 0, stream>>>(xb, wkvt, nullptr, kvb, nullptr, nullptr);
  attn_kernel<<<4096, 256, 0, stream>>>(kvb, qb, mask, yf);
  ln_kernel<<<16384, 256, 0, stream>>>(yf, yb, lng, lnb);
  // G2: (16384x1024) @ (1024x8192) + GLU -> hidden bf16.  grid 64*32 = 2048
  gemm256<1, 1024, 8192><<<2048, 512, 0, stream>>>(yb, w1t, nullptr, hid, b1, nullptr);
  // G3: (16384x4096) @ (4096x1024) + bias + resid -> out.  grid 64*4 = 256
  gemm256<2, 4096, 1024><<<256, 512, 0, stream>>>(hid, w2t, out, nullptr, b2, yf);
}

// Round 6
// 1156.230 us; speedup vs baseline: 6.9508x; 6.9508x over previous
//
#include <hip/hip_runtime.h>
#include <stdint.h>
#include <math.h>

// ---------------- constants ----------------
#define SCALE  0.125f

typedef __bf16 bf16;
typedef __bf16 bf16x8 __attribute__((ext_vector_type(8)));
typedef float  f32x4  __attribute__((ext_vector_type(4)));

__device__ __forceinline__ ushort f2b(float f) {
  union { float f; uint32_t u; } v; v.f = f;
  uint32_t u = v.u;
  return (ushort)((u + 0x7fffu + ((u >> 16) & 1u)) >> 16);
}
__device__ __forceinline__ float b2f(ushort s) {
  union { uint32_t u; float f; } v; v.u = ((uint32_t)s) << 16;
  return v.f;
}
__device__ __forceinline__ void g2l16(const ushort* g, ushort* l) {
  __builtin_amdgcn_global_load_lds(
      (const __attribute__((address_space(1))) void*)g,
      (__attribute__((address_space(3))) void*)l, 16, 0, 0);
}
// A&S 7.1.26 erf, |eps| <= 1.5e-7 (far below bf16 rounding). v_rcp + v_exp.
__device__ __forceinline__ float erf_fast(float x) {
  float ax = fabsf(x);
  float t  = __builtin_amdgcn_rcpf(1.0f + 0.3275911f * ax);
  float p  = t * (0.254829592f + t * (-0.284496736f + t * (1.421413741f +
             t * (-1.453152027f + t * 1.061405429f))));
  float e  = __expf(-ax * ax);
  float r  = 1.0f - p * e;
  return copysignf(r, x);
}

// ---------------- conversion kernels ----------------
// x: (S,B,N,D) f32 -> xb: (S,N,B,D) bf16
__global__ __launch_bounds__(256) void conv_x_kernel(const float* __restrict__ x,
                                                     ushort* __restrict__ xb) {
  int idx = blockIdx.x * 256 + threadIdx.x;
  int d4 = idx & 255;
  int n  = (idx >> 8) & 31;
  int b  = (idx >> 13) & 127;
  int s  = idx >> 20;
  float4 v = *(const float4*)(x + (size_t)(((s*128 + b)*32 + n) << 10) + (d4 << 2));
  ushort4 o;
  o.x = f2b(v.x); o.y = f2b(v.y); o.z = f2b(v.z); o.w = f2b(v.w);
  *(ushort4*)(xb + (size_t)(((s*32 + n)*128 + b) << 10) + (d4 << 2)) = o;
}

__global__ __launch_bounds__(256) void conv_q_kernel(const float* __restrict__ q,
                                                     ushort* __restrict__ qb) {
  int idx = blockIdx.x * 256 + threadIdx.x;
  float4 v = *(const float4*)(q + (size_t)idx * 4);
  ushort4 o;
  o.x = f2b(v.x); o.y = f2b(v.y); o.z = f2b(v.z); o.w = f2b(v.w);
  *(ushort4*)(qb + (size_t)idx * 4) = o;
}

// Wt[r][k] = W[k][srccol(r)] (bf16).
// mode 1 = W1 GLU interleave on 64-row groups: group g6 = r>>6, w = r&63:
//   w<32 -> a col g6*32+w ; w>=32 -> gate col 4096 + g6*32 + (w-32).
__global__ __launch_bounds__(256) void transpose_w_kernel(const float* __restrict__ W,
                                                          ushort* __restrict__ Wt,
                                                          int K, int N, int mode) {
  __shared__ float tile[32][33];
  int rt = blockIdx.x, kt = blockIdx.y;
  int r0 = rt * 32;
  int tx = threadIdx.x & 31, ty = threadIdx.x >> 5;
  int src;
  if (mode == 1) {
    int rp = r0 + tx;
    int g6 = rp >> 6, w = rp & 63;
    src = (w < 32) ? (g6*32 + w) : (4096 + g6*32 + (w - 32));
  } else {
    src = r0 + tx;
  }
  for (int i = ty; i < 32; i += 8)
    tile[i][tx] = W[(size_t)(kt*32 + i) * N + src];
  __syncthreads();
  for (int i = ty; i < 32; i += 8)
    Wt[(size_t)(r0 + i) * K + kt*32 + tx] = f2b(tile[tx][i]);
}

// ---------------- main GEMM: 256x256 tile, A-in-LDS + B-direct-to-regs ------
// bf16 A [MxK] x bf16 Bt [NxK]. 512 threads = 8 waves (2M x 4N); per-wave C =
// 128x64 = 8x4 fragments of 16x16 (mfma_f32_16x16x32_bf16). BK=64.
//
// ROUND-5 LESSON (register budget): __launch_bounds__(512,4) caps the UNIFIED
// VGPR+AGPR budget at 512/4=128/wave (m69 pool = 512/lane/SIMD); acc alone is
// 128 f32 -> total spill, 9.6 GB scratch writes, MfmaUtil 2.6%. The 256² tile
// at 8 waves needs ~220-250 regs -> 2 waves/SIMD is the only legal occupancy.
// This version: launch_bounds(512,2); B SINGLE-buffered in regs (32 regs):
// B(t)[*][kh] dies after the phase that consumes it, so next-tile loads refill
// the same registers in P2 (kh0) / P3 (kh1). Budget ~220 <= 256, no spill.
//
// Traffic split (round-4 lesson: all-LDS was LDS-port-bound at 2300+ cyc vs
// MFMA 2483): A via LDS (128 KB read/tile ~1540 cyc + 256 cyc DMA writes),
// B via VMEM/L1 (parallel port). MFMA is now the longest pole.
//
// LDS layout per tile: row r = 128B = 8 granules of 16B; granule g of row r at
// slot g^(r&7) (bank-conflict-free ds_read_b128; counter-verified 0 conflicts).
// 16x16x32 fragment: lane (qq=lane>>4, c15=lane&15) reads row c15, k-chunk
// kh*32 + qq*8 -> granule kh*4 + qq.
//
// Per-wave vmem issue order per tile t (CFENCE-pinned):
//   P1: A0,A1(next)  P2: A2,A3(next) | B[*][0]<-next  P3: B[*][1]<-next
// Boundary: lgkmcnt(0) (own reads of cur done; WAR vs t+1 staging) +
// vmcnt(8) (retires exactly the 4 A-DMAs -> barrier publishes LDS; leaves the
// 8 B loads in flight, awaited by compiler-inserted vmcnt at t+1 P0/P1 use).
// Last tile wrap-stages tile 0 (dead); final vmcnt(0) before LDS dealloc.
// EPI 0: store bf16 -> outb (stride NCOLS)
// EPI 1: in-register GLU (64-group-interleaved W1t) -> hidden bf16 (stride 4096)
// EPI 2: float out = acc + bias[col] + resid (stride NCOLS)
template <int EPI, int K, int NCOLS>
__global__ __launch_bounds__(512, 2) void gemm256(const ushort* __restrict__ A,
                                                  const ushort* __restrict__ Bt,
                                                  float* __restrict__ outf,
                                                  ushort* __restrict__ outb,
                                                  const float* __restrict__ bias,
                                                  const float* __restrict__ resid) {
  __shared__ ushort As[2][16384];
  constexpr int NT  = K / 64;
  constexpr int nBn = NCOLS / 256;

  // XCD-aware swizzle (all grids are multiples of 8)
  const int nwg = (int)gridDim.x;
  const int bid = (int)blockIdx.x;
  const int wg  = (bid & 7) * (nwg >> 3) + (bid >> 3);
  const int bm = wg / nBn, bn = wg % nBn;

  const int t = threadIdx.x;
  const int wave = t >> 6, lane = t & 63;
  const int wm = wave >> 2, wn = wave & 3;
  const int c15 = lane & 15, qq = lane >> 4;
  const int swz = c15 & 7;

  // A staging: thread t -> row (t>>3) within 64-row call block, slot t&7,
  // source granule (t&7)^(row&7)
  const int rowc = t >> 3;
  const int kg = (t & 7) ^ (rowc & 7);
  const ushort* ag = A + (size_t)(bm*256 + rowc) * K + kg*8;
  // B direct fragment base: row (bn*256 + wn*64 + ni*16 + c15), k-off qq*8
  const ushort* bgf = Bt + (size_t)(bn*256 + wn*64 + c15) * K + qq*8;

  f32x4 acc[8][4] = {};
  bf16x8 bB[4][2];   // single-buffered B fragments (static idx only)

#define LDA_F(buf, mi, kh) \
  (*(const bf16x8*)(&As[buf][(wm*128 + (mi)*16 + c15)*64 + ((((kh)*4 + qq) ^ swz)*8)]))
#define LDBG(ni, kh, kt) \
  (*(const bf16x8*)(bgf + (size_t)(ni)*16*K + (size_t)(kt)*64 + (kh)*32))
#define STG_A(c, buf, kt) \
  g2l16(ag + (size_t)(c)*64*K + (size_t)(kt)*64, &As[buf][(c)*4096 + wave*512])

#define CFENCE asm volatile("" ::: "memory")

#define MFMA8(p, aa, ab, kh) \
  _Pragma("unroll") \
  for (int ni = 0; ni < 4; ++ni) { \
    acc[2*(p)][ni]   = __builtin_amdgcn_mfma_f32_16x16x32_bf16((aa), bB[ni][(kh)], acc[2*(p)][ni],   0, 0, 0); \
    acc[2*(p)+1][ni] = __builtin_amdgcn_mfma_f32_16x16x32_bf16((ab), bB[ni][(kh)], acc[2*(p)+1][ni], 0, 0, 0); \
  }

  // prologue: stage A(tile0); load B(tile0); vmcnt(8) retires the 4 A-DMAs
  STG_A(0, 0, 0); STG_A(1, 0, 0); STG_A(2, 0, 0); STG_A(3, 0, 0);
  CFENCE;
  bB[0][0] = LDBG(0,0,0); bB[1][0] = LDBG(1,0,0);
  bB[2][0] = LDBG(2,0,0); bB[3][0] = LDBG(3,0,0);
  bB[0][1] = LDBG(0,1,0); bB[1][1] = LDBG(1,1,0);
  bB[2][1] = LDBG(2,1,0); bB[3][1] = LDBG(3,1,0);
  asm volatile("s_waitcnt vmcnt(8)" ::: "memory");
  __builtin_amdgcn_s_barrier();
  CFENCE;

#define TILE(kt, cur) { \
    const int nx_ = (cur) ^ 1; \
    const int tn_ = ((kt) + 1 == NT) ? 0 : ((kt) + 1); \
    /* ---- P0: A mi0-3 kh0; MFMA quads 0,1 kh0 (uses bB[*][0]) ---- */ { \
      bf16x8 a0 = LDA_F(cur, 0, 0), a1 = LDA_F(cur, 1, 0); \
      bf16x8 a2 = LDA_F(cur, 2, 0), a3 = LDA_F(cur, 3, 0); \
      __builtin_amdgcn_s_setprio(1); \
      MFMA8(0, a0, a1, 0); MFMA8(1, a2, a3, 0); \
      __builtin_amdgcn_s_setprio(0); \
      __builtin_amdgcn_s_barrier(); \
    } \
    /* ---- P1: A mi0-3 kh1; stage A0,A1(next); MFMA kh1 (bB[*][1]) ---- */ { \
      bf16x8 a0 = LDA_F(cur, 0, 1), a1 = LDA_F(cur, 1, 1); \
      bf16x8 a2 = LDA_F(cur, 2, 1), a3 = LDA_F(cur, 3, 1); \
      STG_A(0, nx_, tn_); STG_A(1, nx_, tn_); \
      __builtin_amdgcn_s_setprio(1); \
      MFMA8(0, a0, a1, 1); MFMA8(1, a2, a3, 1); \
      __builtin_amdgcn_s_setprio(0); \
      __builtin_amdgcn_s_barrier(); \
    } \
    /* ---- P2: A mi4-7 kh0; stage A2,A3(next); MFMA; refill bB[*][0] ---- */ { \
      bf16x8 a0 = LDA_F(cur, 4, 0), a1 = LDA_F(cur, 5, 0); \
      bf16x8 a2 = LDA_F(cur, 6, 0), a3 = LDA_F(cur, 7, 0); \
      STG_A(2, nx_, tn_); STG_A(3, nx_, tn_); \
      CFENCE; \
      __builtin_amdgcn_s_setprio(1); \
      MFMA8(2, a0, a1, 0); MFMA8(3, a2, a3, 0); \
      __builtin_amdgcn_s_setprio(0); \
      bB[0][0] = LDBG(0,0,tn_); bB[1][0] = LDBG(1,0,tn_); \
      bB[2][0] = LDBG(2,0,tn_); bB[3][0] = LDBG(3,0,tn_); \
      __builtin_amdgcn_s_barrier(); \
    } \
    /* ---- P3: A mi4-7 kh1; MFMA; refill bB[*][1]; lgkm0+vmcnt(8)+BAR ---- */ { \
      bf16x8 a0 = LDA_F(cur, 4, 1), a1 = LDA_F(cur, 5, 1); \
      bf16x8 a2 = LDA_F(cur, 6, 1), a3 = LDA_F(cur, 7, 1); \
      __builtin_amdgcn_s_setprio(1); \
      MFMA8(2, a0, a1, 1); MFMA8(3, a2, a3, 1); \
      __builtin_amdgcn_s_setprio(0); \
      bB[0][1] = LDBG(0,1,tn_); bB[1][1] = LDBG(1,1,tn_); \
      bB[2][1] = LDBG(2,1,tn_); bB[3][1] = LDBG(3,1,tn_); \
      asm volatile("s_waitcnt lgkmcnt(0)" ::: "memory"); \
      asm volatile("s_waitcnt vmcnt(8)" ::: "memory"); \
      __builtin_amdgcn_s_barrier(); \
      CFENCE; \
    } \
  }

#pragma unroll 1
  for (int kt = 0; kt < NT; kt += 2) {
    TILE(kt, 0);
    TILE(kt + 1, 1);
  }
  // drain wrap-stage DMAs + B loads before LDS dealloc / epilogue
  asm volatile("s_waitcnt vmcnt(0)" ::: "memory");

#undef TILE
#undef MFMA8
#undef CFENCE
#undef STG_A
#undef LDBG
#undef LDA_F

  // C/D layout (m89/m91): col = lane&15, row = (lane>>4)*4 + reg
  if (EPI == 0) {
#pragma unroll
    for (int mi = 0; mi < 8; ++mi) {
      int row0 = bm*256 + wm*128 + mi*16 + qq*4;
#pragma unroll
      for (int j = 0; j < 4; ++j) {
#pragma unroll
        for (int ni = 0; ni < 4; ++ni) {
          int col = bn*256 + wn*64 + ni*16 + c15;
          outb[(size_t)(row0 + j) * NCOLS + col] = f2b(acc[mi][ni][j]);
        }
      }
    }
  } else if (EPI == 1) {
    // wave's 64-col slice == one GLU 64-group: g6 = bn*4 + wn.
    // ni 0,1 = 'a' (cols g6*32 + ni*16 + c15); ni 2,3 = gate (same hidden col).
    const int g6 = bn*4 + wn;
    const int hcol0 = g6*32 + c15;
    float ba0 = bias[hcol0],        ba1 = bias[hcol0 + 16];
    float bg0 = bias[4096 + hcol0], bg1 = bias[4096 + hcol0 + 16];
#pragma unroll
    for (int mi = 0; mi < 8; ++mi) {
      int row0 = bm*256 + wm*128 + mi*16 + qq*4;
#pragma unroll
      for (int j = 0; j < 4; ++j) {
        float a0 = acc[mi][0][j] + ba0, g0 = acc[mi][2][j] + bg0;
        float a1 = acc[mi][1][j] + ba1, g1 = acc[mi][3][j] + bg1;
        float ge0 = 0.5f * g0 * (1.0f + erf_fast(g0 * 0.70710678118654752f));
        float ge1 = 0.5f * g1 * (1.0f + erf_fast(g1 * 0.70710678118654752f));
        size_t rb = (size_t)(row0 + j) * 4096;
        outb[rb + hcol0]      = f2b(a0 * ge0);
        outb[rb + hcol0 + 16] = f2b(a1 * ge1);
      }
    }
  } else {
    float bc[4];
#pragma unroll
    for (int ni = 0; ni < 4; ++ni) bc[ni] = bias[bn*256 + wn*64 + ni*16 + c15];
#pragma unroll
    for (int mi = 0; mi < 8; ++mi) {
      int row0 = bm*256 + wm*128 + mi*16 + qq*4;
#pragma unroll
      for (int j = 0; j < 4; ++j) {
#pragma unroll
        for (int ni = 0; ni < 4; ++ni) {
          int col = bn*256 + wn*64 + ni*16 + c15;
          size_t o = (size_t)(row0 + j) * NCOLS + col;
          outf[o] = acc[mi][ni][j] + bc[ni] + resid[o];
        }
      }
    }
  }
}

// ---------------- attention ----------------
__global__ __launch_bounds__(256) void attn_kernel(const ushort* __restrict__ kv,
                                                   const ushort* __restrict__ qb,
                                                   const int* __restrict__ mask,
                                                   float* __restrict__ out) {
  __shared__ ushort Ks[128 * 72];
  __shared__ ushort Vt[64 * 136];
  __shared__ ushort Ps[64 * 136];
  __shared__ float  Mrow[128];

  const int bid = blockIdx.x;
  const int h = bid & 15, n = (bid >> 4) & 31, s = bid >> 9;
  const size_t kvbase = (size_t)((s*32 + n) * 128) * 2048;
  const int t = threadIdx.x, wave = t >> 6, lane = t & 63;
  const int qq = lane >> 4, r = lane & 15;

  if (t < 128) Mrow[t] = (mask[s*128 + t] == 0) ? 1.0f : 0.0f;

  for (int c = t; c < 1024; c += 256) {
    int b = c >> 3, d0 = (c & 7) * 8;
    uint4 v = *(const uint4*)(kv + kvbase + (size_t)b * 2048 + h*64 + d0);
    *(uint4*)(Ks + b*72 + d0) = v;
  }
  {
    int b = t & 127, dh = t >> 7;
    for (int jj = 0; jj < 32; jj += 8) {
      uint4 v = *(const uint4*)(kv + kvbase + (size_t)b * 2048 + 1024 + h*64 + dh*32 + jj);
      const ushort* pv = (const ushort*)&v;
#pragma unroll
      for (int u8 = 0; u8 < 8; u8++)
        Vt[(dh*32 + jj + u8)*136 + b] = pv[u8];
    }
  }
  __syncthreads();

  bf16x8 aq[2];
#pragma unroll
  for (int st = 0; st < 2; st++)
    aq[st] = *(const bf16x8*)(qb + (size_t)(wave*16 + r) * 1024 + h*64 + st*32 + qq*8);
  f32x4 sim[8];
#pragma unroll
  for (int jt = 0; jt < 8; jt++) {
    f32x4 c = {};
#pragma unroll
    for (int st = 0; st < 2; st++) {
      bf16x8 bk = *(const bf16x8*)(Ks + (jt*16 + r)*72 + st*32 + qq*8);
      c = __builtin_amdgcn_mfma_f32_16x16x32_bf16(aq[st], bk, c, 0, 0, 0);
    }
    sim[jt] = c;
  }

#pragma unroll
  for (int jt = 0; jt < 8; jt++) {
    float mflag = Mrow[jt*16 + r];
#pragma unroll
    for (int ii = 0; ii < 4; ii++) {
      float v = sim[jt][ii] * SCALE;
      sim[jt][ii] = (mflag > 0.5f) ? -1e10f : v;
    }
  }
  float mx[4] = {-3.0e38f, -3.0e38f, -3.0e38f, -3.0e38f};
#pragma unroll
  for (int jt = 0; jt < 8; jt++)
#pragma unroll
    for (int ii = 0; ii < 4; ii++) mx[ii] = fmaxf(mx[ii], sim[jt][ii]);
#pragma unroll
  for (int m = 1; m < 16; m <<= 1)
#pragma unroll
    for (int ii = 0; ii < 4; ii++) mx[ii] = fmaxf(mx[ii], __shfl_xor(mx[ii], m));
  float sm[4] = {0.f, 0.f, 0.f, 0.f};
#pragma unroll
  for (int jt = 0; jt < 8; jt++)
#pragma unroll
    for (int ii = 0; ii < 4; ii++) {
      float e = expf(sim[jt][ii] - mx[ii]);
      sim[jt][ii] = e;
      sm[ii] += e;
    }
#pragma unroll
  for (int m = 1; m < 16; m <<= 1)
#pragma unroll
    for (int ii = 0; ii < 4; ii++) sm[ii] += __shfl_xor(sm[ii], m);
#pragma unroll
  for (int ii = 0; ii < 4; ii++) sm[ii] = 1.0f / sm[ii];
#pragma unroll
  for (int jt = 0; jt < 8; jt++)
#pragma unroll
    for (int ii = 0; ii < 4; ii++)
      Ps[(wave*16 + qq*4 + ii)*136 + jt*16 + r] = f2b(sim[jt][ii] * sm[ii]);
  __syncthreads();

  f32x4 o[4] = {};
#pragma unroll
  for (int kst = 0; kst < 4; kst++) {
    bf16x8 ap = *(const bf16x8*)(Ps + (wave*16 + r)*136 + kst*32 + qq*8);
#pragma unroll
    for (int jt2 = 0; jt2 < 4; jt2++) {
      bf16x8 bv = *(const bf16x8*)(Vt + (jt2*16 + r)*136 + kst*32 + qq*8);
      o[jt2] = __builtin_amdgcn_mfma_f32_16x16x32_bf16(ap, bv, o[jt2], 0, 0, 0);
    }
  }
  const size_t orow0 = (size_t)((s*32 + n) * 64);
#pragma unroll
  for (int jt2 = 0; jt2 < 4; jt2++)
#pragma unroll
    for (int ii = 0; ii < 4; ii++) {
      int qr = wave*16 + qq*4 + ii;
      int d  = jt2*16 + r;
      out[(orow0 + qr) * 1024 + h*64 + d] = o[jt2][ii];
    }
}

// ---------------- LayerNorm (in-place) + bf16 copy ----------------
__global__ __launch_bounds__(256) void ln_kernel(float* __restrict__ y,
                                                 ushort* __restrict__ yb,
                                                 const float* __restrict__ g,
                                                 const float* __restrict__ b) {
  __shared__ float r1[4], r2[4];
  const int row = blockIdx.x, t = threadIdx.x;
  const int wave = t >> 6, lane = t & 63;
  float* p = y + (size_t)row * 1024;
  float4 v = *(const float4*)(p + t*4);
  float s1 = v.x + v.y + v.z + v.w;
  float s2 = v.x*v.x + v.y*v.y + v.z*v.z + v.w*v.w;
#pragma unroll
  for (int m = 1; m < 64; m <<= 1) { s1 += __shfl_xor(s1, m); s2 += __shfl_xor(s2, m); }
  if (lane == 0) { r1[wave] = s1; r2[wave] = s2; }
  __syncthreads();
  s1 = r1[0] + r1[1] + r1[2] + r1[3];
  s2 = r2[0] + r2[1] + r2[2] + r2[3];
  float mu  = s1 * (1.0f/1024.0f);
  float var = s2 * (1.0f/1024.0f) - mu*mu;
  float inv = rsqrtf(var + 1e-5f);
  float4 gg = *(const float4*)(g + t*4);
  float4 bb = *(const float4*)(b + t*4);
  float4 o;
  o.x = (v.x - mu)*inv*gg.x + bb.x;
  o.y = (v.y - mu)*inv*gg.y + bb.y;
  o.z = (v.z - mu)*inv*gg.z + bb.z;
  o.w = (v.w - mu)*inv*gg.w + bb.w;
  *(float4*)(p + t*4) = o;
  ushort4 ob; ob.x = f2b(o.x); ob.y = f2b(o.y); ob.z = f2b(o.z); ob.w = f2b(o.w);
  *(ushort4*)(yb + (size_t)row * 1024 + t*4) = ob;
}

// ---------------- launcher ----------------
extern "C" void kernel_launch(void* const* d_in, const int* in_sizes, int n_in,
                              void* d_out, int out_size, void* d_ws, size_t ws_size,
                              hipStream_t stream) {
  const float* x    = (const float*)d_in[0];
  const int*   mask = (const int*)  d_in[1];
  const float* q    = (const float*)d_in[2];
  const float* Wkv  = (const float*)d_in[3];
  const float* lng  = (const float*)d_in[4];
  const float* lnb  = (const float*)d_in[5];
  const float* W1   = (const float*)d_in[6];
  const float* b1   = (const float*)d_in[7];
  const float* W2   = (const float*)d_in[8];
  const float* b2   = (const float*)d_in[9];
  float* out = (float*)d_out;
  char* ws = (char*)d_ws;

  ushort* xb   = (ushort*)(ws);               // 64 MiB; dead after G1
  float*  yf   = (float*) (ws);               // alias: attn out / y
  ushort* kvb  = (ushort*)(ws + 67108864);    // 128 MiB; dead after attn
  ushort* hid  = (ushort*)(ws + 67108864);    // alias: hidden bf16
  ushort* yb   = (ushort*)(ws + 201326592);   // 32 MiB
  ushort* wkvt = (ushort*)(ws + 234881024);   // 4 MiB
  ushort* w1t  = (ushort*)(ws + 239075328);   // 16 MiB (GLU 64-group interleave)
  ushort* w2t  = (ushort*)(ws + 255852544);   // 8 MiB
  ushort* qb   = (ushort*)(ws + 264241152);   // 128 KiB

  conv_x_kernel<<<32768, 256, 0, stream>>>(x, xb);
  conv_q_kernel<<<64, 256, 0, stream>>>(q, qb);
  transpose_w_kernel<<<dim3(64, 32),  256, 0, stream>>>(Wkv, wkvt, 1024, 2048, 0);
  transpose_w_kernel<<<dim3(256, 32), 256, 0, stream>>>(W1,  w1t,  1024, 8192, 1);
  transpose_w_kernel<<<dim3(32, 128), 256, 0, stream>>>(W2,  w2t,  4096, 1024, 0);

  // G1: (32768x1024) @ (1024x2048) -> kv bf16.  grid 128*8 = 1024
  gemm256<0, 1024, 2048><<<1024, 512, 0, stream>>>(xb, wkvt, nullptr, kvb, nullptr, nullptr);
  attn_kernel<<<4096, 256, 0, stream>>>(kvb, qb, mask, yf);
  ln_kernel<<<16384, 256, 0, stream>>>(yf, yb, lng, lnb);
  // G2: (16384x1024) @ (1024x8192) + GLU -> hidden bf16.  grid 64*32 = 2048
  gemm256<1, 1024, 8192><<<2048, 512, 0, stream>>>(yb, w1t, nullptr, hid, b1, nullptr);
  // G3: (16384x4096) @ (4096x1024) + bias + resid -> out.  grid 64*4 = 256
  gemm256<2, 4096, 1024><<<256, 512, 0, stream>>>(hid, w2t, out, nullptr, b2, yf);
}

// Round 7
// 921.992 us; speedup vs baseline: 8.7167x; 1.2541x over previous
//
#include <hip/hip_runtime.h>
#include <stdint.h>
#include <math.h>

// ---------------- constants ----------------
#define SCALE  0.125f

typedef __bf16 bf16;
typedef __bf16 bf16x8 __attribute__((ext_vector_type(8)));
typedef float  f32x4  __attribute__((ext_vector_type(4)));

__device__ __forceinline__ ushort f2b(float f) {
  union { float f; uint32_t u; } v; v.f = f;
  uint32_t u = v.u;
  return (ushort)((u + 0x7fffu + ((u >> 16) & 1u)) >> 16);
}
__device__ __forceinline__ float b2f(ushort s) {
  union { uint32_t u; float f; } v; v.u = ((uint32_t)s) << 16;
  return v.f;
}
__device__ __forceinline__ void g2l16(const ushort* g, ushort* l) {
  __builtin_amdgcn_global_load_lds(
      (const __attribute__((address_space(1))) void*)g,
      (__attribute__((address_space(3))) void*)l, 16, 0, 0);
}
// A&S 7.1.26 erf, |eps| <= 1.5e-7 (far below bf16 rounding). v_rcp + v_exp.
__device__ __forceinline__ float erf_fast(float x) {
  float ax = fabsf(x);
  float t  = __builtin_amdgcn_rcpf(1.0f + 0.3275911f * ax);
  float p  = t * (0.254829592f + t * (-0.284496736f + t * (1.421413741f +
             t * (-1.453152027f + t * 1.061405429f))));
  float e  = __expf(-ax * ax);
  float r  = 1.0f - p * e;
  return copysignf(r, x);
}

// ---------------- conversion kernels ----------------
// x: (S,B,N,D) f32 -> xb: (S,N,B,D) bf16
__global__ __launch_bounds__(256) void conv_x_kernel(const float* __restrict__ x,
                                                     ushort* __restrict__ xb) {
  int idx = blockIdx.x * 256 + threadIdx.x;
  int d4 = idx & 255;
  int n  = (idx >> 8) & 31;
  int b  = (idx >> 13) & 127;
  int s  = idx >> 20;
  float4 v = *(const float4*)(x + (size_t)(((s*128 + b)*32 + n) << 10) + (d4 << 2));
  ushort4 o;
  o.x = f2b(v.x); o.y = f2b(v.y); o.z = f2b(v.z); o.w = f2b(v.w);
  *(ushort4*)(xb + (size_t)(((s*32 + n)*128 + b) << 10) + (d4 << 2)) = o;
}

__global__ __launch_bounds__(256) void conv_q_kernel(const float* __restrict__ q,
                                                     ushort* __restrict__ qb) {
  int idx = blockIdx.x * 256 + threadIdx.x;
  float4 v = *(const float4*)(q + (size_t)idx * 4);
  ushort4 o;
  o.x = f2b(v.x); o.y = f2b(v.y); o.z = f2b(v.z); o.w = f2b(v.w);
  *(ushort4*)(qb + (size_t)idx * 4) = o;
}

// Wt[r][k] = W[k][srccol(r)] (bf16).
// mode 1 = W1 GLU interleave on 64-row groups: group g6 = r>>6, w = r&63:
//   w<32 -> a col g6*32+w ; w>=32 -> gate col 4096 + g6*32 + (w-32).
__global__ __launch_bounds__(256) void transpose_w_kernel(const float* __restrict__ W,
                                                          ushort* __restrict__ Wt,
                                                          int K, int N, int mode) {
  __shared__ float tile[32][33];
  int rt = blockIdx.x, kt = blockIdx.y;
  int r0 = rt * 32;
  int tx = threadIdx.x & 31, ty = threadIdx.x >> 5;
  int src;
  if (mode == 1) {
    int rp = r0 + tx;
    int g6 = rp >> 6, w = rp & 63;
    src = (w < 32) ? (g6*32 + w) : (4096 + g6*32 + (w - 32));
  } else {
    src = r0 + tx;
  }
  for (int i = ty; i < 32; i += 8)
    tile[i][tx] = W[(size_t)(kt*32 + i) * N + src];
  __syncthreads();
  for (int i = ty; i < 32; i += 8)
    Wt[(size_t)(r0 + i) * K + kt*32 + tx] = f2b(tile[tx][i]);
}

// ---------------- main GEMM: 256x256 tile, deep-prefetch 2-barrier pipeline --
// bf16 A [MxK] x bf16 Bt [NxK]. 512 threads = 8 waves (2M x 4N); per-wave C =
// 128x64 = 8x4 fragments of 16x16 (mfma_f32_16x16x32_bf16). BK=64.
// LDS: A,B double-buffered K-tiles (2 x 32KB each = 128 KiB, 1 block/CU).
// LDS layout per tile: row r = 128B = 8 granules of 16B; granule g of row r at
// slot g^(r&7) (bank-conflict-free ds_read_b128; counter-verified 0 conflicts).
// 16x16x32 fragment: lane (qq=lane>>4, c15=lane&15) reads row c15, k-chunk
// kh*32 + qq*8 -> granule kh*4 + qq.
//
// ROUND-6 LESSONS:
//  - B must stay in LDS: per-lane B-fragment global gather (16 rows x 2KB
//    stride per instr) is transaction-bound (MfmaUtil 26%). r3 all-LDS base.
//  - r3's residual ~1500 cyc/tile stall is staging-load latency: FETCH 547MB
//    vs ~48MB ideal -> frequent L2 misses (~900 cyc); r3's prefetch distance
//    (0.5-0.75 tile) and boundary vmcnt(2) gave ~1 phase of slack.
// THIS VERSION:
//  - Deep prefetch: ALL 8 staging DMAs for tile t+1 issue at t.P0. By the
//    boundary they are ~4 phases (~3500cyc) old -> boundary drain is cheap
//    even on HBM miss. Single publication point: lgkm0 + vmcnt(0) + barrier.
//    (lgkm0 = own reads of cur done -> WAR-safe vs t+1 staging into cur;
//    vmcnt(0) = all t+1 data in LDS; barrier = publish to all waves.)
//    Mid-tile counted vmcnts and issue-order fences are gone (nothing to
//    count); keep r3's 2-barrier pacing (end-P1, end-P3 boundary).
//  - 4x4 intra-XCD block grouping: within each XCD's contiguous wg-window
//    (cpx = nwg/8 blocks = R x nBn full rows; R,nBn divisible by 4 for all
//    three shapes), walk in 4bm x 4bn squares -> ~4MB L2 working set/square.
// EPI 0: store bf16 -> outb (stride NCOLS)
// EPI 1: in-register GLU (64-group-interleaved W1t) -> hidden bf16 (stride 4096)
// EPI 2: float out = acc + bias[col] + resid (stride NCOLS)
template <int EPI, int K, int NCOLS>
__global__ __launch_bounds__(512, 2) void gemm256(const ushort* __restrict__ A,
                                                  const ushort* __restrict__ Bt,
                                                  float* __restrict__ outf,
                                                  ushort* __restrict__ outb,
                                                  const float* __restrict__ bias,
                                                  const float* __restrict__ resid) {
  __shared__ ushort As[2][16384];
  __shared__ ushort Bs[2][16384];
  constexpr int NT  = K / 64;
  constexpr int nBn = NCOLS / 256;
  constexpr int SQR = nBn / 4;           // 4x4 squares per bn-row of a window

  // XCD-aware chunking + 4x4 grouping (bijective; all grids %8==0,
  // cpx%nBn==0, nBn%4==0, (cpx/nBn)%4==0 for G1/G2/G3)
  const int nwg = (int)gridDim.x;
  const int cpx = nwg >> 3;
  const int bid = (int)blockIdx.x;
  const int chunk = bid & 7, c = bid >> 3;
  const int s4 = c >> 4, u4 = c & 15;
  const int rl = (s4 / SQR) * 4 + (u4 >> 2);
  const int bl = (s4 % SQR) * 4 + (u4 & 3);
  const int wg = chunk * cpx + rl * nBn + bl;
  const int bm = wg / nBn, bn = wg % nBn;

  const int t = threadIdx.x;
  const int wave = t >> 6, lane = t & 63;
  const int wm = wave >> 2, wn = wave & 3;
  const int c15 = lane & 15, qq = lane >> 4;
  const int swz = c15 & 7;

  // staging: thread t -> row (t>>3) within 64-row call block, slot t&7,
  // source granule (t&7)^(row&7)
  const int rowc = t >> 3;
  const int kg = (t & 7) ^ (rowc & 7);
  const ushort* ag = A  + (size_t)(bm*256 + rowc) * K + kg*8;
  const ushort* bg = Bt + (size_t)(bn*256 + rowc) * K + kg*8;

  f32x4 acc[8][4] = {};

#define LDA_F(buf, mi, kh) \
  (*(const bf16x8*)(&As[buf][(wm*128 + (mi)*16 + c15)*64 + ((((kh)*4 + qq) ^ swz)*8)]))
#define LDB_F(buf, ni, kh) \
  (*(const bf16x8*)(&Bs[buf][(wn*64 + (ni)*16 + c15)*64 + ((((kh)*4 + qq) ^ swz)*8)]))
#define STG_A(c, buf, kt) \
  g2l16(ag + (size_t)(c)*64*K + (size_t)(kt)*64, &As[buf][(c)*4096 + wave*512])
#define STG_B(c, buf, kt) \
  g2l16(bg + (size_t)(c)*64*K + (size_t)(kt)*64, &Bs[buf][(c)*4096 + wave*512])

#define CFENCE asm volatile("" ::: "memory")

#define MFMA8(p, aa, ab, kh) \
  _Pragma("unroll") \
  for (int ni = 0; ni < 4; ++ni) { \
    acc[2*(p)][ni]   = __builtin_amdgcn_mfma_f32_16x16x32_bf16((aa), bfv[ni][(kh)], acc[2*(p)][ni],   0, 0, 0); \
    acc[2*(p)+1][ni] = __builtin_amdgcn_mfma_f32_16x16x32_bf16((ab), bfv[ni][(kh)], acc[2*(p)+1][ni], 0, 0, 0); \
  }

  // prologue: stage tile 0 fully; drain; publish
  STG_B(0, 0, 0); STG_B(1, 0, 0); STG_B(2, 0, 0); STG_B(3, 0, 0);
  STG_A(0, 0, 0); STG_A(1, 0, 0); STG_A(2, 0, 0); STG_A(3, 0, 0);
  asm volatile("s_waitcnt vmcnt(0)" ::: "memory");
  __builtin_amdgcn_s_barrier();
  CFENCE;

#define TILE(kt, cur) { \
    const int nx_ = (cur) ^ 1; \
    const int tn_ = ((kt) + 1 == NT) ? 0 : ((kt) + 1); \
    bf16x8 bfv[4][2]; \
    /* ---- P0: B kh0 + A mi0-3 kh0; issue ALL 8 stages(t+1); MFMA ---- */ { \
      _Pragma("unroll") \
      for (int ni = 0; ni < 4; ++ni) bfv[ni][0] = LDB_F(cur, ni, 0); \
      bf16x8 a0 = LDA_F(cur, 0, 0), a1 = LDA_F(cur, 1, 0); \
      bf16x8 a2 = LDA_F(cur, 2, 0), a3 = LDA_F(cur, 3, 0); \
      STG_B(0, nx_, tn_); STG_B(1, nx_, tn_); STG_B(2, nx_, tn_); STG_B(3, nx_, tn_); \
      STG_A(0, nx_, tn_); STG_A(1, nx_, tn_); STG_A(2, nx_, tn_); STG_A(3, nx_, tn_); \
      __builtin_amdgcn_s_setprio(1); \
      MFMA8(0, a0, a1, 0); MFMA8(1, a2, a3, 0); \
      __builtin_amdgcn_s_setprio(0); \
    } \
    /* ---- P1: B kh1 + A mi0-3 kh1; MFMA; BARRIER (pacing) ---- */ { \
      _Pragma("unroll") \
      for (int ni = 0; ni < 4; ++ni) bfv[ni][1] = LDB_F(cur, ni, 1); \
      bf16x8 a0 = LDA_F(cur, 0, 1), a1 = LDA_F(cur, 1, 1); \
      bf16x8 a2 = LDA_F(cur, 2, 1), a3 = LDA_F(cur, 3, 1); \
      __builtin_amdgcn_s_setprio(1); \
      MFMA8(0, a0, a1, 1); MFMA8(1, a2, a3, 1); \
      __builtin_amdgcn_s_setprio(0); \
      __builtin_amdgcn_s_barrier(); \
      CFENCE; \
    } \
    /* ---- P2: A mi4-7 kh0; MFMA ---- */ { \
      bf16x8 a0 = LDA_F(cur, 4, 0), a1 = LDA_F(cur, 5, 0); \
      bf16x8 a2 = LDA_F(cur, 6, 0), a3 = LDA_F(cur, 7, 0); \
      __builtin_amdgcn_s_setprio(1); \
      MFMA8(2, a0, a1, 0); MFMA8(3, a2, a3, 0); \
      __builtin_amdgcn_s_setprio(0); \
      CFENCE; \
    } \
    /* ---- P3: A mi4-7 kh1; MFMA; lgkm0 + vmcnt(0) + BARRIER ---- */ { \
      bf16x8 a0 = LDA_F(cur, 4, 1), a1 = LDA_F(cur, 5, 1); \
      bf16x8 a2 = LDA_F(cur, 6, 1), a3 = LDA_F(cur, 7, 1); \
      __builtin_amdgcn_s_setprio(1); \
      MFMA8(2, a0, a1, 1); MFMA8(3, a2, a3, 1); \
      __builtin_amdgcn_s_setprio(0); \
      asm volatile("s_waitcnt lgkmcnt(0)" ::: "memory"); \
      asm volatile("s_waitcnt vmcnt(0)" ::: "memory"); \
      __builtin_amdgcn_s_barrier(); \
      CFENCE; \
    } \
  }

#pragma unroll 1
  for (int kt = 0; kt < NT; kt += 2) {
    TILE(kt, 0);
    TILE(kt + 1, 1);
  }
  // all wrap-stage DMAs already drained by the last boundary vmcnt(0)

#undef TILE
#undef MFMA8
#undef CFENCE
#undef STG_A
#undef STG_B
#undef LDA_F
#undef LDB_F

  // C/D layout (m89/m91): col = lane&15, row = (lane>>4)*4 + reg
  if (EPI == 0) {
#pragma unroll
    for (int mi = 0; mi < 8; ++mi) {
      int row0 = bm*256 + wm*128 + mi*16 + qq*4;
#pragma unroll
      for (int j = 0; j < 4; ++j) {
#pragma unroll
        for (int ni = 0; ni < 4; ++ni) {
          int col = bn*256 + wn*64 + ni*16 + c15;
          outb[(size_t)(row0 + j) * NCOLS + col] = f2b(acc[mi][ni][j]);
        }
      }
    }
  } else if (EPI == 1) {
    // wave's 64-col slice == one GLU 64-group: g6 = bn*4 + wn.
    // ni 0,1 = 'a' (cols g6*32 + ni*16 + c15); ni 2,3 = gate (same hidden col).
    const int g6 = bn*4 + wn;
    const int hcol0 = g6*32 + c15;
    float ba0 = bias[hcol0],        ba1 = bias[hcol0 + 16];
    float bg0 = bias[4096 + hcol0], bg1 = bias[4096 + hcol0 + 16];
#pragma unroll
    for (int mi = 0; mi < 8; ++mi) {
      int row0 = bm*256 + wm*128 + mi*16 + qq*4;
#pragma unroll
      for (int j = 0; j < 4; ++j) {
        float a0 = acc[mi][0][j] + ba0, g0 = acc[mi][2][j] + bg0;
        float a1 = acc[mi][1][j] + ba1, g1 = acc[mi][3][j] + bg1;
        float ge0 = 0.5f * g0 * (1.0f + erf_fast(g0 * 0.70710678118654752f));
        float ge1 = 0.5f * g1 * (1.0f + erf_fast(g1 * 0.70710678118654752f));
        size_t rb = (size_t)(row0 + j) * 4096;
        outb[rb + hcol0]      = f2b(a0 * ge0);
        outb[rb + hcol0 + 16] = f2b(a1 * ge1);
      }
    }
  } else {
    float bc[4];
#pragma unroll
    for (int ni = 0; ni < 4; ++ni) bc[ni] = bias[bn*256 + wn*64 + ni*16 + c15];
#pragma unroll
    for (int mi = 0; mi < 8; ++mi) {
      int row0 = bm*256 + wm*128 + mi*16 + qq*4;
#pragma unroll
      for (int j = 0; j < 4; ++j) {
#pragma unroll
        for (int ni = 0; ni < 4; ++ni) {
          int col = bn*256 + wn*64 + ni*16 + c15;
          size_t o = (size_t)(row0 + j) * NCOLS + col;
          outf[o] = acc[mi][ni][j] + bc[ni] + resid[o];
        }
      }
    }
  }
}

// ---------------- attention ----------------
__global__ __launch_bounds__(256) void attn_kernel(const ushort* __restrict__ kv,
                                                   const ushort* __restrict__ qb,
                                                   const int* __restrict__ mask,
                                                   float* __restrict__ out) {
  __shared__ ushort Ks[128 * 72];
  __shared__ ushort Vt[64 * 136];
  __shared__ ushort Ps[64 * 136];
  __shared__ float  Mrow[128];

  const int bid = blockIdx.x;
  const int h = bid & 15, n = (bid >> 4) & 31, s = bid >> 9;
  const size_t kvbase = (size_t)((s*32 + n) * 128) * 2048;
  const int t = threadIdx.x, wave = t >> 6, lane = t & 63;
  const int qq = lane >> 4, r = lane & 15;

  if (t < 128) Mrow[t] = (mask[s*128 + t] == 0) ? 1.0f : 0.0f;

  for (int c = t; c < 1024; c += 256) {
    int b = c >> 3, d0 = (c & 7) * 8;
    uint4 v = *(const uint4*)(kv + kvbase + (size_t)b * 2048 + h*64 + d0);
    *(uint4*)(Ks + b*72 + d0) = v;
  }
  {
    int b = t & 127, dh = t >> 7;
    for (int jj = 0; jj < 32; jj += 8) {
      uint4 v = *(const uint4*)(kv + kvbase + (size_t)b * 2048 + 1024 + h*64 + dh*32 + jj);
      const ushort* pv = (const ushort*)&v;
#pragma unroll
      for (int u8 = 0; u8 < 8; u8++)
        Vt[(dh*32 + jj + u8)*136 + b] = pv[u8];
    }
  }
  __syncthreads();

  bf16x8 aq[2];
#pragma unroll
  for (int st = 0; st < 2; st++)
    aq[st] = *(const bf16x8*)(qb + (size_t)(wave*16 + r) * 1024 + h*64 + st*32 + qq*8);
  f32x4 sim[8];
#pragma unroll
  for (int jt = 0; jt < 8; jt++) {
    f32x4 c = {};
#pragma unroll
    for (int st = 0; st < 2; st++) {
      bf16x8 bk = *(const bf16x8*)(Ks + (jt*16 + r)*72 + st*32 + qq*8);
      c = __builtin_amdgcn_mfma_f32_16x16x32_bf16(aq[st], bk, c, 0, 0, 0);
    }
    sim[jt] = c;
  }

#pragma unroll
  for (int jt = 0; jt < 8; jt++) {
    float mflag = Mrow[jt*16 + r];
#pragma unroll
    for (int ii = 0; ii < 4; ii++) {
      float v = sim[jt][ii] * SCALE;
      sim[jt][ii] = (mflag > 0.5f) ? -1e10f : v;
    }
  }
  float mx[4] = {-3.0e38f, -3.0e38f, -3.0e38f, -3.0e38f};
#pragma unroll
  for (int jt = 0; jt < 8; jt++)
#pragma unroll
    for (int ii = 0; ii < 4; ii++) mx[ii] = fmaxf(mx[ii], sim[jt][ii]);
#pragma unroll
  for (int m = 1; m < 16; m <<= 1)
#pragma unroll
    for (int ii = 0; ii < 4; ii++) mx[ii] = fmaxf(mx[ii], __shfl_xor(mx[ii], m));
  float sm[4] = {0.f, 0.f, 0.f, 0.f};
#pragma unroll
  for (int jt = 0; jt < 8; jt++)
#pragma unroll
    for (int ii = 0; ii < 4; ii++) {
      float e = expf(sim[jt][ii] - mx[ii]);
      sim[jt][ii] = e;
      sm[ii] += e;
    }
#pragma unroll
  for (int m = 1; m < 16; m <<= 1)
#pragma unroll
    for (int ii = 0; ii < 4; ii++) sm[ii] += __shfl_xor(sm[ii], m);
#pragma unroll
  for (int ii = 0; ii < 4; ii++) sm[ii] = 1.0f / sm[ii];
#pragma unroll
  for (int jt = 0; jt < 8; jt++)
#pragma unroll
    for (int ii = 0; ii < 4; ii++)
      Ps[(wave*16 + qq*4 + ii)*136 + jt*16 + r] = f2b(sim[jt][ii] * sm[ii]);
  __syncthreads();

  f32x4 o[4] = {};
#pragma unroll
  for (int kst = 0; kst < 4; kst++) {
    bf16x8 ap = *(const bf16x8*)(Ps + (wave*16 + r)*136 + kst*32 + qq*8);
#pragma unroll
    for (int jt2 = 0; jt2 < 4; jt2++) {
      bf16x8 bv = *(const bf16x8*)(Vt + (jt2*16 + r)*136 + kst*32 + qq*8);
      o[jt2] = __builtin_amdgcn_mfma_f32_16x16x32_bf16(ap, bv, o[jt2], 0, 0, 0);
    }
  }
  const size_t orow0 = (size_t)((s*32 + n) * 64);
#pragma unroll
  for (int jt2 = 0; jt2 < 4; jt2++)
#pragma unroll
    for (int ii = 0; ii < 4; ii++) {
      int qr = wave*16 + qq*4 + ii;
      int d  = jt2*16 + r;
      out[(orow0 + qr) * 1024 + h*64 + d] = o[jt2][ii];
    }
}

// ---------------- LayerNorm (in-place) + bf16 copy ----------------
__global__ __launch_bounds__(256) void ln_kernel(float* __restrict__ y,
                                                 ushort* __restrict__ yb,
                                                 const float* __restrict__ g,
                                                 const float* __restrict__ b) {
  __shared__ float r1[4], r2[4];
  const int row = blockIdx.x, t = threadIdx.x;
  const int wave = t >> 6, lane = t & 63;
  float* p = y + (size_t)row * 1024;
  float4 v = *(const float4*)(p + t*4);
  float s1 = v.x + v.y + v.z + v.w;
  float s2 = v.x*v.x + v.y*v.y + v.z*v.z + v.w*v.w;
#pragma unroll
  for (int m = 1; m < 64; m <<= 1) { s1 += __shfl_xor(s1, m); s2 += __shfl_xor(s2, m); }
  if (lane == 0) { r1[wave] = s1; r2[wave] = s2; }
  __syncthreads();
  s1 = r1[0] + r1[1] + r1[2] + r1[3];
  s2 = r2[0] + r2[1] + r2[2] + r2[3];
  float mu  = s1 * (1.0f/1024.0f);
  float var = s2 * (1.0f/1024.0f) - mu*mu;
  float inv = rsqrtf(var + 1e-5f);
  float4 gg = *(const float4*)(g + t*4);
  float4 bb = *(const float4*)(b + t*4);
  float4 o;
  o.x = (v.x - mu)*inv*gg.x + bb.x;
  o.y = (v.y - mu)*inv*gg.y + bb.y;
  o.z = (v.z - mu)*inv*gg.z + bb.z;
  o.w = (v.w - mu)*inv*gg.w + bb.w;
  *(float4*)(p + t*4) = o;
  ushort4 ob; ob.x = f2b(o.x); ob.y = f2b(o.y); ob.z = f2b(o.z); ob.w = f2b(o.w);
  *(ushort4*)(yb + (size_t)row * 1024 + t*4) = ob;
}

// ---------------- launcher ----------------
extern "C" void kernel_launch(void* const* d_in, const int* in_sizes, int n_in,
                              void* d_out, int out_size, void* d_ws, size_t ws_size,
                              hipStream_t stream) {
  const float* x    = (const float*)d_in[0];
  const int*   mask = (const int*)  d_in[1];
  const float* q    = (const float*)d_in[2];
  const float* Wkv  = (const float*)d_in[3];
  const float* lng  = (const float*)d_in[4];
  const float* lnb  = (const float*)d_in[5];
  const float* W1   = (const float*)d_in[6];
  const float* b1   = (const float*)d_in[7];
  const float* W2   = (const float*)d_in[8];
  const float* b2   = (const float*)d_in[9];
  float* out = (float*)d_out;
  char* ws = (char*)d_ws;

  ushort* xb   = (ushort*)(ws);               // 64 MiB; dead after G1
  float*  yf   = (float*) (ws);               // alias: attn out / y
  ushort* kvb  = (ushort*)(ws + 67108864);    // 128 MiB; dead after attn
  ushort* hid  = (ushort*)(ws + 67108864);    // alias: hidden bf16
  ushort* yb   = (ushort*)(ws + 201326592);   // 32 MiB
  ushort* wkvt = (ushort*)(ws + 234881024);   // 4 MiB
  ushort* w1t  = (ushort*)(ws + 239075328);   // 16 MiB (GLU 64-group interleave)
  ushort* w2t  = (ushort*)(ws + 255852544);   // 8 MiB
  ushort* qb   = (ushort*)(ws + 264241152);   // 128 KiB

  conv_x_kernel<<<32768, 256, 0, stream>>>(x, xb);
  conv_q_kernel<<<64, 256, 0, stream>>>(q, qb);
  transpose_w_kernel<<<dim3(64, 32),  256, 0, stream>>>(Wkv, wkvt, 1024, 2048, 0);
  transpose_w_kernel<<<dim3(256, 32), 256, 0, stream>>>(W1,  w1t,  1024, 8192, 1);
  transpose_w_kernel<<<dim3(32, 128), 256, 0, stream>>>(W2,  w2t,  4096, 1024, 0);

  // G1: (32768x1024) @ (1024x2048) -> kv bf16.  grid 128*8 = 1024
  gemm256<0, 1024, 2048><<<1024, 512, 0, stream>>>(xb, wkvt, nullptr, kvb, nullptr, nullptr);
  attn_kernel<<<4096, 256, 0, stream>>>(kvb, qb, mask, yf);
  ln_kernel<<<16384, 256, 0, stream>>>(yf, yb, lng, lnb);
  // G2: (16384x1024) @ (1024x8192) + GLU -> hidden bf16.  grid 64*32 = 2048
  gemm256<1, 1024, 8192><<<2048, 512, 0, stream>>>(yb, w1t, nullptr, hid, b1, nullptr);
  // G3: (16384x4096) @ (4096x1024) + bias + resid -> out.  grid 64*4 = 256
  gemm256<2, 4096, 1024><<<256, 512, 0, stream>>>(hid, w2t, out, nullptr, b2, yf);
}